// Round 19
// baseline (429.949 us; speedup 1.0000x reference)
//
#include <hip/hip_runtime.h>
#include <stdint.h>

// KVCacheAttention: B=4, Sq=2048, Scache=6144, Skv=8192, D=1024, scale=1/8.
// Round 19: r18 + PV rebuilt as a dedicated kernel (256q x 128d tile, full
// K=8192, grid (8,8,4)=256wg=1/CU) with normalization fused -> split-K
// partials (67MB) and k_reduce (100MB traffic + dispatch) eliminated.
// PV K-loop = r13 quadrant rhythm re-derived: A halves interleaved
// (row'=mh*128+wr*32+r) so all waves read both halves; stage A0(2),B0(1),
// B1(1),A1(2); VMC4@p0/VMC3@p1/VMC3@p3 certification chain (each read
// certified by a PREVIOUS phase's VMC+barrier -- r14 lesson).

#define DM 1024
#define NB 4
#define SQN 2048
#define SCC 6144
#define SKV 8192

typedef unsigned short u16;
typedef __attribute__((ext_vector_type(8))) short short8;
typedef __attribute__((ext_vector_type(4))) float f32x4;

__device__ __forceinline__ u16 f2bf(float x) {
  unsigned u = __builtin_bit_cast(unsigned, x);
  u += 0x7fffu + ((u >> 16) & 1u);  // RNE; inputs finite
  return (u16)(u >> 16);
}

__device__ __forceinline__ ushort4 cv4(float4 v) {
  ushort4 u;
  u.x = f2bf(v.x); u.y = f2bf(v.y); u.z = f2bf(v.z); u.w = f2bf(v.w);
  return u;
}

__device__ __forceinline__ void gll16(const void* g, void* l) {
  __builtin_amdgcn_global_load_lds(
      (const __attribute__((address_space(1))) void*)g,
      (__attribute__((address_space(3))) void*)l, 16, 0, 0);
}

#define FENCE() asm volatile("" ::: "memory")
#define BARRIER()                      \
  do {                                 \
    FENCE();                           \
    __builtin_amdgcn_s_barrier();      \
    FENCE();                           \
  } while (0)

#define DSR(d, a, I) \
  asm volatile("ds_read_b128 %0, %1 offset:%2" : "=v"(d) : "v"(a), "i"(I))

#define VMCN(N) asm volatile("s_waitcnt vmcnt(" #N ")" ::: "memory")
#define LGKM0()                                        \
  do {                                                 \
    asm volatile("s_waitcnt lgkmcnt(0)" ::: "memory"); \
    __builtin_amdgcn_sched_barrier(0);                 \
  } while (0)

// ---------------- fused prep: conversions + sums zero ----------------
__global__ __launch_bounds__(256) void k_prep(
    const float* __restrict__ hidden, const float* __restrict__ Wq,
    const float* __restrict__ Wk, const float* __restrict__ Wv,
    const float* __restrict__ ck, u16* __restrict__ Hb,
    u16* __restrict__ Wall, u16* __restrict__ Kb, float* __restrict__ sums) {
  const long NH = (long)NB * SQN * DM / 4;
  const long NW = (long)DM * DM / 4;
  const long NC = (long)NB * SCC * DM / 4;
  const long T1 = NH + 3 * NW;
  const long T2 = T1 + NC;
  const long T3 = T2 + (long)NB * SQN / 4;
  long i = (long)blockIdx.x * 256 + threadIdx.x;
  const long st = (long)gridDim.x * 256;
  for (; i < T3; i += st) {
    if (i < NH) {
      ((ushort4*)Hb)[i] = cv4(((const float4*)hidden)[i]);
    } else if (i < T1) {
      long r = i - NH;
      int w = (int)(r / NW);
      long o = r - (long)w * NW;
      const float* src = w == 0 ? Wq : (w == 1 ? Wk : Wv);
      ((ushort4*)Wall)[r] = cv4(((const float4*)src)[o]);
    } else if (i < T2) {
      long r = i - T1;
      float4 v = ((const float4*)ck)[r];
      long e = r * 4;
      int b = (int)(e / ((long)SCC * DM));
      long rem = e - (long)b * SCC * DM;
      *(ushort4*)(Kb + (long)b * SKV * DM + rem) = cv4(v);
    } else {
      float4 z;
      z.x = 0.f; z.y = 0.f; z.z = 0.f; z.w = 0.f;
      ((float4*)sums)[i - T2] = z;
    }
  }
}

// ---------------- V^T builder (cached region only: kv < SCC) ----------------
__global__ __launch_bounds__(256) void k_build_vt(const float* __restrict__ cv,
                                                  u16* __restrict__ VT) {
  __shared__ u16 t[64][65];
  const int kv0 = blockIdx.x * 64;
  const int d0 = blockIdx.y * 64;
  const int b = blockIdx.z;
  const int c = threadIdx.x & 63;
  const int r4 = threadIdx.x >> 6;
#pragma unroll
  for (int p = 0; p < 16; ++p) {
    int kr = p * 4 + r4;
    t[kr][c] = f2bf(cv[((long)b * SCC + kv0 + kr) * DM + d0 + c]);
  }
  __syncthreads();
#pragma unroll
  for (int p = 0; p < 16; ++p) {
    int dr = p * 4 + r4;
    VT[((long)b * DM + d0 + dr) * SKV + kv0 + c] = t[c][dr];
  }
}

// ---------------- 256x256xBK64 quadrant-phase NT GEMM (r13/r18) ----------------
// MODE0: QKV projection (A=W-stack, B=H; V third writes VT directly).
// MODE1: S^T = K.Q^T + exp + rowsums (transposed grid).
template <int MODE>
__global__ __launch_bounds__(512, 2) void k_gemm8(
    const u16* __restrict__ A, const u16* __restrict__ B0,
    void* __restrict__ C0, void* __restrict__ C1, void* __restrict__ C2,
    float* __restrict__ sums, const float* __restrict__ bias0,
    const float* __restrict__ bias1, const float* __restrict__ bias2) {
  extern __shared__ char smem[];
  const int tid = threadIdx.x;
  const int lane = tid & 63;
  const int wv = tid >> 6;   // 0..7
  const int wr = wv >> 2;    // 0..1
  const int wc = wv & 3;     // 0..3
  const int bm = (MODE == 1 ? blockIdx.x : blockIdx.y) * 256;  // A rows
  const int bn = (MODE == 1 ? blockIdx.y : blockIdx.x) * 256;  // B rows
  const int z = blockIdx.z;

  constexpr int LD = DM;
  constexpr int NT = DM / 64;

  const u16 *Ab_, *Bb_;
  if constexpr (MODE == 0) {
    Ab_ = A + (long)bm * LD;          // W-stack rows: out-d
    Bb_ = B0 + (long)bn * LD;         // H tokens
  } else {
    Ab_ = A + ((long)z * SKV + bm) * LD;   // K rows: kv
    Bb_ = B0 + ((long)z * SQN + bn) * LD;  // Q rows: q
  }

  const int sg = tid >> 3;                     // 0..63
  const int ssl = ((tid & 7) ^ (sg & 7)) * 8;  // pre-swizzled col (elems)
  const u16* gA[2][2];
  const u16* gB[2][2];
#pragma unroll
  for (int mh = 0; mh < 2; ++mh)
#pragma unroll
    for (int g = 0; g < 2; ++g) {
      gA[mh][g] = Ab_ + (long)(g * 128 + mh * 64 + sg) * LD + ssl;
      gB[mh][g] = Bb_ + (long)((g * 2 + (sg >> 5)) * 64 + mh * 32 + (sg & 31)) * LD + ssl;
    }
  u16* lA = (u16*)smem + tid * 8;
  u16* lB = (u16*)smem + 32768 + tid * 8;

#define SA(MH, BUFN, KO)                                              \
  do {                                                                \
    gll16(gA[MH][0] + (KO), lA + (BUFN)*16384 + (MH)*8192);           \
    gll16(gA[MH][1] + (KO), lA + (BUFN)*16384 + (MH)*8192 + 4096);    \
  } while (0)
#define SB(NH, BUFN, KO)                                              \
  do {                                                                \
    gll16(gB[NH][0] + (KO), lB + (BUFN)*16384 + (NH)*8192);           \
    gll16(gB[NH][1] + (KO), lB + (BUFN)*16384 + (NH)*8192 + 4096);    \
  } while (0)

  SA(0, 0, 0);
  SB(0, 0, 0);
  SB(1, 0, 0);
  SA(1, 0, 0);
  VMCN(4);
  BARRIER();

  f32x4 acc[8][4];
#pragma unroll
  for (int m = 0; m < 8; ++m)
#pragma unroll
    for (int n = 0; n < 4; ++n)
#pragma unroll
      for (int j = 0; j < 4; ++j) acc[m][n][j] = 0.0f;

  const int alane = lane & 15;
  const int sw = lane & 7;
  const int s0 = lane >> 4;
  const int slot0 = ((s0 ^ sw) * 16);
  const int slot1 = (((s0 + 4) ^ sw) * 16);
  const int aBase = (wr * 64 + alane) * 128;
  const int bBase = (wc * 32 + alane) * 128;

  short8 aF[4][2];
  short8 bF[2][2][2];

#define ARD8(MH, AR0, AR1)                           \
  _Pragma("unroll") for (int ms = 0; ms < 4; ++ms) { \
    DSR(aF[ms][0], AR0, (MH)*16384 + ms * 2048);     \
    DSR(aF[ms][1], AR1, (MH)*16384 + ms * 2048);     \
  }
#define BRD4(NH, BR0, BR1)                           \
  _Pragma("unroll") for (int ns = 0; ns < 2; ++ns) { \
    DSR(bF[NH][ns][0], BR0, (NH)*16384 + ns * 2048); \
    DSR(bF[NH][ns][1], BR1, (NH)*16384 + ns * 2048); \
  }
#define MFMA_Q(MH, NH)                                                     \
  do {                                                                     \
    __builtin_amdgcn_s_setprio(1);                                         \
    _Pragma("unroll") for (int ms = 0; ms < 4; ++ms)                       \
    _Pragma("unroll") for (int ns = 0; ns < 2; ++ns)                       \
    _Pragma("unroll") for (int kk = 0; kk < 2; ++kk)                       \
        acc[(MH)*4 + ms][(NH)*2 + ns] =                                    \
            __builtin_amdgcn_mfma_f32_16x16x32_bf16(                       \
                aF[ms][kk], bF[NH][ns][kk], acc[(MH)*4 + ms][(NH)*2 + ns], \
                0, 0, 0);                                                  \
    __builtin_amdgcn_s_setprio(0);                                         \
    __builtin_amdgcn_sched_barrier(0);                                     \
  } while (0)

#define TILE_BODY(BUF, KT)                                            \
  do {                                                                \
    const long ko = (long)(((KT) + 1 < NT) ? (KT) + 1 : (KT)) * 64;   \
    const int aR0 = (BUF)*32768 + aBase + slot0;                      \
    const int aR1 = (BUF)*32768 + aBase + slot1;                      \
    const int bR0 = 65536 + (BUF)*32768 + bBase + slot0;              \
    const int bR1 = 65536 + (BUF)*32768 + bBase + slot1;              \
    ARD8(0, aR0, aR1);                                                \
    BRD4(0, bR0, bR1);                                                \
    SA(0, (BUF) ^ 1, ko);                                             \
    VMCN(4);                                                          \
    BARRIER();                                                        \
    LGKM0();                                                          \
    MFMA_Q(0, 0);                                                     \
    BRD4(1, bR0, bR1);                                                \
    SB(0, (BUF) ^ 1, ko);                                             \
    VMCN(4);                                                          \
    BARRIER();                                                        \
    LGKM0();                                                          \
    MFMA_Q(0, 1);                                                     \
    ARD8(1, aR0, aR1);                                                \
    SB(1, (BUF) ^ 1, ko);                                             \
    BARRIER();                                                        \
    LGKM0();                                                          \
    MFMA_Q(1, 1);                                                     \
    SA(1, (BUF) ^ 1, ko);                                             \
    VMCN(4);                                                          \
    BARRIER();                                                        \
    MFMA_Q(1, 0);                                                     \
  } while (0)

  for (int t2 = 0; t2 < NT; t2 += 2) {
    TILE_BODY(0, t2);
    TILE_BODY(1, t2 + 1);
  }
#undef TILE_BODY
#undef ARD8
#undef BRD4
#undef MFMA_Q
#undef SA
#undef SB

  const int rsub = (lane >> 4) * 4;

  if constexpr (MODE == 0) {
    const int which = bm >> 10;
    const float* bp = which == 0 ? bias0 : (which == 1 ? bias1 : bias2);
    u16* Cq = (u16*)C0;
    u16* Ck = (u16*)C1;
    u16* Cvt = (u16*)C2;  // VT base [b][d][kv]
    const int od_base = (bm & 1023) + wr * 128 + rsub;
    if (which == 2) {
#pragma unroll
      for (int n = 0; n < 4; ++n) {
        int token = bn + wc * 64 + n * 16 + alane;
        int b = token >> 11, ss = token & 2047;
        u16* vtb = Cvt + (long)b * DM * SKV + SCC + ss;
#pragma unroll
        for (int m = 0; m < 8; ++m) {
          int cc = od_base + m * 16;
          float4 bb = *(const float4*)(bp + cc);
          float bv4[4] = {bb.x, bb.y, bb.z, bb.w};
#pragma unroll
          for (int jj = 0; jj < 4; ++jj)
            vtb[(long)(cc + jj) * SKV] = f2bf(acc[m][n][jj] + bv4[jj]);
        }
      }
    } else {
#pragma unroll
      for (int n = 0; n < 4; ++n) {
        int token = bn + wc * 64 + n * 16 + alane;
        u16* dst;
        if (which == 1) {
          int b = token >> 11, ss = token & 2047;
          dst = Ck + ((long)b * SKV + SCC + ss) * DM;
        } else {
          dst = Cq + (long)token * DM;
        }
#pragma unroll
        for (int m = 0; m < 8; ++m) {
          int cc = od_base + m * 16;
          float4 bb = *(const float4*)(bp + cc);
          ushort4 u;
          u.x = f2bf(acc[m][n][0] + bb.x);
          u.y = f2bf(acc[m][n][1] + bb.y);
          u.z = f2bf(acc[m][n][2] + bb.z);
          u.w = f2bf(acc[m][n][3] + bb.w);
          *(ushort4*)(dst + cc) = u;
        }
      }
    }
  } else {
    u16* Pp = (u16*)C0 + (long)z * SQN * SKV;
    float* sb = sums + z * SQN;
    const float CE = 0.18033688011112042f;  // log2(e)/8
    const int kv_base = bm + wr * 128 + rsub;
#pragma unroll
    for (int n = 0; n < 4; ++n) {
      int q = bn + wc * 64 + n * 16 + alane;
      u16* prow = Pp + (long)q * SKV;
      float part = 0.f;
#pragma unroll
      for (int m = 0; m < 8; ++m) {
        int kv = kv_base + m * 16;
        float e0 = exp2f(acc[m][n][0] * CE);
        float e1 = exp2f(acc[m][n][1] * CE);
        float e2 = exp2f(acc[m][n][2] * CE);
        float e3 = exp2f(acc[m][n][3] * CE);
        part += (e0 + e1) + (e2 + e3);
        ushort4 u;
        u.x = f2bf(e0); u.y = f2bf(e1); u.z = f2bf(e2); u.w = f2bf(e3);
        *(ushort4*)(prow + kv) = u;
      }
      part += __shfl_xor(part, 16);
      part += __shfl_xor(part, 32);
      if ((lane >> 4) == 0) atomicAdd(&sb[q], part);
    }
  }
}

// ---------------- PV: 256q x 128d, full K=8192, normalize fused ----------------
// 8 waves = 4wr(q) x 2wc(d); per-wave 64x64, acc[4][4].
// LDS 96 KiB: A[2buf][2half][128r][64k] @0 (64 KB; half mh holds rows
// {wr*64+mh*32+r} interleaved so every wave reads both halves), B[2buf][2half]
// [64r][64k] @65536 (32 KB; nh holds rows {wc*64+nh*32+r}).
// Stage/tile: SA0(2)@p0, SB0(1)@p1, SB1(1)@p2, SA1(2)@p3.
// Certification: VMC4@p0 drains B1(t) (p1 reads), VMC3@p1 drains A1(t)
// (p2 reads), VMC3@p3 drains A0,B0(t+1) (p0(t+1) reads). Reads pre-barrier.
__global__ __launch_bounds__(512, 2) void k_pv(
    const u16* __restrict__ P, const u16* __restrict__ VT,
    const float* __restrict__ sums, float* __restrict__ out) {
  extern __shared__ char smem[];
  const int tid = threadIdx.x;
  const int lane = tid & 63;
  const int wv = tid >> 6;   // 0..7
  const int wr = wv >> 1;    // 0..3 (q band)
  const int wc = wv & 1;     // 0..1 (d half)
  const int bm = blockIdx.y * 256;  // q
  const int bn = blockIdx.x * 128;  // d
  const int z = blockIdx.z;
  constexpr int NT = SKV / 64;  // 128

  const u16* Ab_ = P + ((long)z * SQN + bm) * (long)SKV;
  const u16* Bb_ = VT + ((long)z * DM + bn) * (long)SKV;

  const int sg = tid >> 3;
  const int ssl = ((tid & 7) ^ (sg & 7)) * 8;
  const u16* gA[2][2];  // [mh][g]: grow = (g*2+(sg>>5))*64 + mh*32 + (sg&31)
  const u16* gB[2];     // [nh]:    grow = (sg>>5)*64 + nh*32 + (sg&31)
#pragma unroll
  for (int mh = 0; mh < 2; ++mh)
#pragma unroll
    for (int g = 0; g < 2; ++g)
      gA[mh][g] = Ab_ + (long)((g * 2 + (sg >> 5)) * 64 + mh * 32 + (sg & 31)) * SKV + ssl;
#pragma unroll
  for (int nh = 0; nh < 2; ++nh)
    gB[nh] = Bb_ + (long)((sg >> 5) * 64 + nh * 32 + (sg & 31)) * SKV + ssl;

  u16* lA = (u16*)smem + tid * 8;           // + buf*16384 + mh*8192 + g*4096
  u16* lB = (u16*)smem + 32768 + tid * 8;   // + buf*8192 + nh*4096

#define SAP(MH, BUFN, KO)                                             \
  do {                                                                \
    gll16(gA[MH][0] + (KO), lA + (BUFN)*16384 + (MH)*8192);           \
    gll16(gA[MH][1] + (KO), lA + (BUFN)*16384 + (MH)*8192 + 4096);    \
  } while (0)
#define SBP(NH, BUFN, KO) \
  gll16(gB[NH] + (KO), lB + (BUFN)*8192 + (NH)*4096)

  // prologue: stage tile 0; drain A0(2)+B0(1) -> vmcnt(3)
  SAP(0, 0, 0);
  SBP(0, 0, 0);
  SBP(1, 0, 0);
  SAP(1, 0, 0);
  VMCN(3);
  BARRIER();

  f32x4 acc[4][4];
#pragma unroll
  for (int m = 0; m < 4; ++m)
#pragma unroll
    for (int n = 0; n < 4; ++n)
#pragma unroll
      for (int j = 0; j < 4; ++j) acc[m][n][j] = 0.0f;

  const int alane = lane & 15;
  const int sw = lane & 7;
  const int s0 = lane >> 4;
  const int slot0 = ((s0 ^ sw) * 16);
  const int slot1 = (((s0 + 4) ^ sw) * 16);
  const int aBase = (wr * 32 + alane) * 128;  // + mh*16384 + ml*2048 (bytes)
  const int bBase = (wc * 32 + alane) * 128;  // + nh*8192 + nl*2048 (bytes)

  short8 aF[2][2];     // [ml][kk], current mh
  short8 bF[2][2][2];  // [nh][nl][kk]

#define ARD4(MH, AR0, AR1)                           \
  _Pragma("unroll") for (int ml = 0; ml < 2; ++ml) { \
    DSR(aF[ml][0], AR0, (MH)*16384 + ml * 2048);     \
    DSR(aF[ml][1], AR1, (MH)*16384 + ml * 2048);     \
  }
#define BRD4P(NH, BR0, BR1)                          \
  _Pragma("unroll") for (int nl = 0; nl < 2; ++nl) { \
    DSR(bF[NH][nl][0], BR0, (NH)*8192 + nl * 2048);  \
    DSR(bF[NH][nl][1], BR1, (NH)*8192 + nl * 2048);  \
  }
#define MFMA_Q8(MH, NH)                                                    \
  do {                                                                     \
    __builtin_amdgcn_s_setprio(1);                                         \
    _Pragma("unroll") for (int ml = 0; ml < 2; ++ml)                       \
    _Pragma("unroll") for (int nl = 0; nl < 2; ++nl)                       \
    _Pragma("unroll") for (int kk = 0; kk < 2; ++kk)                       \
        acc[(MH)*2 + ml][(NH)*2 + nl] =                                    \
            __builtin_amdgcn_mfma_f32_16x16x32_bf16(                       \
                aF[ml][kk], bF[NH][nl][kk], acc[(MH)*2 + ml][(NH)*2 + nl], \
                0, 0, 0);                                                  \
    __builtin_amdgcn_s_setprio(0);                                         \
    __builtin_amdgcn_sched_barrier(0);                                     \
  } while (0)

#define TILE_PV(BUF, KT)                                              \
  do {                                                                \
    const long ko = (long)(((KT) + 1 < NT) ? (KT) + 1 : (KT)) * 64;   \
    const int aR0 = (BUF)*32768 + aBase + slot0;                      \
    const int aR1 = (BUF)*32768 + aBase + slot1;                      \
    const int bR0 = 65536 + (BUF)*16384 + bBase + slot0;              \
    const int bR1 = 65536 + (BUF)*16384 + bBase + slot1;              \
    /* p0: Q(mh0,nh0) */                                              \
    ARD4(0, aR0, aR1);                                                \
    BRD4P(0, bR0, bR1);                                               \
    SAP(0, (BUF) ^ 1, ko);                                            \
    VMCN(4);                                                          \
    BARRIER();                                                        \
    LGKM0();                                                          \
    MFMA_Q8(0, 0);                                                    \
    /* p1: Q(mh0,nh1) */                                              \
    BRD4P(1, bR0, bR1);                                               \
    SBP(0, (BUF) ^ 1, ko);                                            \
    VMCN(3);                                                          \
    BARRIER();                                                        \
    LGKM0();                                                          \
    MFMA_Q8(0, 1);                                                    \
    /* p2: Q(mh1,nh1) */                                              \
    ARD4(1, aR0, aR1);                                                \
    SBP(1, (BUF) ^ 1, ko);                                            \
    BARRIER();                                                        \
    LGKM0();                                                          \
    MFMA_Q8(1, 1);                                                    \
    /* p3: Q(mh1,nh0) */                                              \
    SAP(1, (BUF) ^ 1, ko);                                            \
    VMCN(3);                                                          \
    BARRIER();                                                        \
    MFMA_Q8(1, 0);                                                    \
  } while (0)

  for (int t2 = 0; t2 < NT; t2 += 2) {
    TILE_PV(0, t2);
    TILE_PV(1, t2 + 1);
  }
#undef TILE_PV
#undef ARD4
#undef BRD4P
#undef MFMA_Q8
#undef SAP
#undef SBP

  // epilogue: O = acc / sums, f32 64B-sector stores direct to out
  const int rsub = (lane >> 4) * 4;
  float* Cp = out + (long)z * SQN * DM;
  const float* sb = sums + z * SQN;
#pragma unroll
  for (int m = 0; m < 4; ++m)
#pragma unroll
    for (int j = 0; j < 4; ++j) {
      int row = bm + wr * 64 + m * 16 + rsub + j;
      float inv = 1.0f / sb[row];
#pragma unroll
      for (int n = 0; n < 4; ++n) {
        int col = bn + wc * 64 + n * 16 + alane;
        Cp[(long)row * DM + col] = acc[m][n][j] * inv;
      }
    }
}

// ---------------- launch ----------------
extern "C" void kernel_launch(void* const* d_in, const int* in_sizes, int n_in,
                              void* d_out, int out_size, void* d_ws, size_t ws_size,
                              hipStream_t stream) {
  const float* hidden = (const float*)d_in[0];
  const float* ck = (const float*)d_in[1];
  const float* cv = (const float*)d_in[2];
  const float* Wq = (const float*)d_in[3];
  const float* bq = (const float*)d_in[4];
  const float* Wk = (const float*)d_in[5];
  const float* bk = (const float*)d_in[6];
  const float* Wv = (const float*)d_in[7];
  const float* bv = (const float*)d_in[8];
  (void)in_sizes; (void)n_in; (void)out_size; (void)ws_size;

  hipFuncSetAttribute(reinterpret_cast<const void*>(&k_gemm8<0>),
                      hipFuncAttributeMaxDynamicSharedMemorySize, 131072);
  hipFuncSetAttribute(reinterpret_cast<const void*>(&k_gemm8<1>),
                      hipFuncAttributeMaxDynamicSharedMemorySize, 131072);
  hipFuncSetAttribute(reinterpret_cast<const void*>(&k_pv),
                      hipFuncAttributeMaxDynamicSharedMemorySize, 98304);

  char* base = (char*)d_ws;
  size_t off = 0;
  auto alloc = [&](size_t bytes) {
    char* p = base + off;
    off = (off + bytes + 255) & ~(size_t)255;
    return p;
  };
  u16* Hb = (u16*)alloc((size_t)NB * SQN * DM * 2);
  u16* Wall = (u16*)alloc((size_t)3 * DM * DM * 2);  // Wq|Wk|Wv stacked
  u16* Qb = (u16*)alloc((size_t)NB * SQN * DM * 2);
  u16* Kb = (u16*)alloc((size_t)NB * SKV * DM * 2);
  u16* VT = (u16*)alloc((size_t)NB * DM * SKV * 2);
  u16* P = (u16*)alloc((size_t)NB * SQN * SKV * 2);
  float* sums = (float*)alloc((size_t)NB * SQN * 4);

  // fused prep: all conversions + sums zeroing in one dispatch
  k_prep<<<2048, 256, 0, stream>>>(hidden, Wq, Wk, Wv, ck, Hb, Wall, Kb, sums);

  // fused QKV projection: A=W-stack [3072][1024], B=H [8192][1024];
  // V third writes VT[.., SCC..SKV) directly.
  k_gemm8<0><<<dim3(32, 12, 1), 512, 131072, stream>>>(
      Wall, Hb, Qb, Kb, VT, nullptr, bq, bk, bv);

  // V^T cached region (kv < SCC)
  k_build_vt<<<dim3(SCC / 64, DM / 64, NB), 256, 0, stream>>>(cv, VT);

  // S^T = K.Q^T, transposed grid: x walks K-panels, y holds Q-panel
  k_gemm8<1><<<dim3(SKV / 256, SQN / 256, NB), 512, 131072, stream>>>(
      Kb, Qb, P, nullptr, nullptr, sums, nullptr, nullptr, nullptr);

  // PV full-K with fused normalization -> d_out directly
  k_pv<<<dim3(DM / 128, SQN / 256, NB), 512, 98304, stream>>>(
      P, VT, sums, (float*)d_out);
}

// Round 20
// 402.883 us; speedup vs baseline: 1.0672x; 1.0672x over previous
//
#include <hip/hip_runtime.h>
#include <stdint.h>

// KVCacheAttention: B=4, Sq=2048, Scache=6144, Skv=8192, D=1024, scale=1/8.
// FINAL (= round 18, best measured 404 us): quadrant-phase 256x256xBK64
// bf16 MFMA GEMMs (pre-barrier ds_reads, counted VMC4 staging chain, row&7
// XOR swizzle -> 0 bank conflicts, setprio), fused prep, V^T written
// directly from the QKV epilogue, S with fused exp+rowsums, PV split-K(2)
// + reduce/normalize. r19's full-K PV regressed (P re-read x8 -> 558MB
// FETCH, HBM-bound); split-K's partial round-trip is the cheaper dataflow.

#define DM 1024
#define NB 4
#define SQN 2048
#define SCC 6144
#define SKV 8192
#define NSPLIT 2
#define KSP (SKV / NSPLIT)

typedef unsigned short u16;
typedef __attribute__((ext_vector_type(8))) short short8;
typedef __attribute__((ext_vector_type(4))) float f32x4;

__device__ __forceinline__ u16 f2bf(float x) {
  unsigned u = __builtin_bit_cast(unsigned, x);
  u += 0x7fffu + ((u >> 16) & 1u);  // RNE; inputs finite
  return (u16)(u >> 16);
}

__device__ __forceinline__ ushort4 cv4(float4 v) {
  ushort4 u;
  u.x = f2bf(v.x); u.y = f2bf(v.y); u.z = f2bf(v.z); u.w = f2bf(v.w);
  return u;
}

__device__ __forceinline__ void gll16(const void* g, void* l) {
  __builtin_amdgcn_global_load_lds(
      (const __attribute__((address_space(1))) void*)g,
      (__attribute__((address_space(3))) void*)l, 16, 0, 0);
}

#define FENCE() asm volatile("" ::: "memory")
#define BARRIER()                      \
  do {                                 \
    FENCE();                           \
    __builtin_amdgcn_s_barrier();      \
    FENCE();                           \
  } while (0)

#define DSR(d, a, I) \
  asm volatile("ds_read_b128 %0, %1 offset:%2" : "=v"(d) : "v"(a), "i"(I))

#define VMC4() asm volatile("s_waitcnt vmcnt(4)" ::: "memory")
#define LGKM0()                                        \
  do {                                                 \
    asm volatile("s_waitcnt lgkmcnt(0)" ::: "memory"); \
    __builtin_amdgcn_sched_barrier(0);                 \
  } while (0)

// ---------------- fused prep: conversions + sums zero ----------------
__global__ __launch_bounds__(256) void k_prep(
    const float* __restrict__ hidden, const float* __restrict__ Wq,
    const float* __restrict__ Wk, const float* __restrict__ Wv,
    const float* __restrict__ ck, u16* __restrict__ Hb,
    u16* __restrict__ Wall, u16* __restrict__ Kb, float* __restrict__ sums) {
  const long NH = (long)NB * SQN * DM / 4;
  const long NW = (long)DM * DM / 4;
  const long NC = (long)NB * SCC * DM / 4;
  const long T1 = NH + 3 * NW;
  const long T2 = T1 + NC;
  const long T3 = T2 + (long)NB * SQN / 4;
  long i = (long)blockIdx.x * 256 + threadIdx.x;
  const long st = (long)gridDim.x * 256;
  for (; i < T3; i += st) {
    if (i < NH) {
      ((ushort4*)Hb)[i] = cv4(((const float4*)hidden)[i]);
    } else if (i < T1) {
      long r = i - NH;
      int w = (int)(r / NW);
      long o = r - (long)w * NW;
      const float* src = w == 0 ? Wq : (w == 1 ? Wk : Wv);
      ((ushort4*)Wall)[r] = cv4(((const float4*)src)[o]);
    } else if (i < T2) {
      long r = i - T1;
      float4 v = ((const float4*)ck)[r];
      long e = r * 4;
      int b = (int)(e / ((long)SCC * DM));
      long rem = e - (long)b * SCC * DM;
      *(ushort4*)(Kb + (long)b * SKV * DM + rem) = cv4(v);
    } else {
      float4 z;
      z.x = 0.f; z.y = 0.f; z.z = 0.f; z.w = 0.f;
      ((float4*)sums)[i - T2] = z;
    }
  }
}

// ---------------- V^T builder (cached region only: kv < SCC) ----------------
__global__ __launch_bounds__(256) void k_build_vt(const float* __restrict__ cv,
                                                  u16* __restrict__ VT) {
  __shared__ u16 t[64][65];
  const int kv0 = blockIdx.x * 64;
  const int d0 = blockIdx.y * 64;
  const int b = blockIdx.z;
  const int c = threadIdx.x & 63;
  const int r4 = threadIdx.x >> 6;
#pragma unroll
  for (int p = 0; p < 16; ++p) {
    int kr = p * 4 + r4;
    t[kr][c] = f2bf(cv[((long)b * SCC + kv0 + kr) * DM + d0 + c]);
  }
  __syncthreads();
#pragma unroll
  for (int p = 0; p < 16; ++p) {
    int dr = p * 4 + r4;
    VT[((long)b * DM + d0 + dr) * SKV + kv0 + c] = t[c][dr];
  }
}

// ---------------- 256x256xBK64 quadrant-phase NT GEMM ----------------
// 512 thr = 8 waves (2M x 4N); per-wave out 128x64.
// LDS 128 KiB: A[2buf][2half][128r][64k] @0, B same @65536.
// 16B slot ^= row&7 via pre-swizzled source; linear gll16 dests.
// MODE1 grid transposed (bm=x over SKV) for L2 Q-panel sharing.
template <int MODE>
__global__ __launch_bounds__(512, 2) void k_gemm8(
    const u16* __restrict__ A, const u16* __restrict__ B0,
    void* __restrict__ C0, void* __restrict__ C1, void* __restrict__ C2,
    float* __restrict__ sums, const float* __restrict__ bias0,
    const float* __restrict__ bias1, const float* __restrict__ bias2) {
  extern __shared__ char smem[];
  const int tid = threadIdx.x;
  const int lane = tid & 63;
  const int wv = tid >> 6;   // 0..7
  const int wr = wv >> 2;    // 0..1
  const int wc = wv & 3;     // 0..3
  const int bm = (MODE == 1 ? blockIdx.x : blockIdx.y) * 256;  // A rows
  const int bn = (MODE == 1 ? blockIdx.y : blockIdx.x) * 256;  // B rows
  const int z = blockIdx.z;

  constexpr int LD = (MODE == 2) ? SKV : DM;
  constexpr int NT = ((MODE == 2) ? KSP : DM) / 64;

  const u16 *Ab_, *Bb_;
  if constexpr (MODE == 0) {
    Ab_ = A + (long)bm * LD;          // W-stack rows: out-d
    Bb_ = B0 + (long)bn * LD;         // H tokens
  } else if constexpr (MODE == 1) {
    Ab_ = A + ((long)z * SKV + bm) * LD;   // K rows: kv
    Bb_ = B0 + ((long)z * SQN + bn) * LD;  // Q rows: q
  } else {
    const int bb_ = z / NSPLIT, sp = z % NSPLIT;
    Ab_ = A + ((long)bb_ * SQN + bm) * (long)SKV + (long)sp * KSP;
    Bb_ = B0 + ((long)bb_ * DM + bn) * (long)SKV + (long)sp * KSP;
  }

  // ---- staging addresses (per-lane global, linear LDS dest) ----
  const int sg = tid >> 3;                     // 0..63
  const int ssl = ((tid & 7) ^ (sg & 7)) * 8;  // pre-swizzled col (elems)
  const u16* gA[2][2];  // [mh][g]: grow = g*128 + mh*64 + sg
  const u16* gB[2][2];  // [nh][g]: grow = (g*2 + (sg>>5))*64 + nh*32 + (sg&31)
#pragma unroll
  for (int mh = 0; mh < 2; ++mh)
#pragma unroll
    for (int g = 0; g < 2; ++g) {
      gA[mh][g] = Ab_ + (long)(g * 128 + mh * 64 + sg) * LD + ssl;
      gB[mh][g] = Bb_ + (long)((g * 2 + (sg >> 5)) * 64 + mh * 32 + (sg & 31)) * LD + ssl;
    }
  u16* lA = (u16*)smem + tid * 8;           // + bufN*16384 + mh*8192 + g*4096
  u16* lB = (u16*)smem + 32768 + tid * 8;

#define SA(MH, BUFN, KO)                                              \
  do {                                                                \
    gll16(gA[MH][0] + (KO), lA + (BUFN)*16384 + (MH)*8192);           \
    gll16(gA[MH][1] + (KO), lA + (BUFN)*16384 + (MH)*8192 + 4096);    \
  } while (0)
#define SB(NH, BUFN, KO)                                              \
  do {                                                                \
    gll16(gB[NH][0] + (KO), lB + (BUFN)*16384 + (NH)*8192);           \
    gll16(gB[NH][1] + (KO), lB + (BUFN)*16384 + (NH)*8192 + 4096);    \
  } while (0)

  // prologue: stage tile 0 halves A0,B0,B1,A1; VMC4 -> A0,B0 certified
  SA(0, 0, 0);
  SB(0, 0, 0);
  SB(1, 0, 0);
  SA(1, 0, 0);
  VMC4();
  BARRIER();

  f32x4 acc[8][4];
#pragma unroll
  for (int m = 0; m < 8; ++m)
#pragma unroll
    for (int n = 0; n < 4; ++n)
#pragma unroll
      for (int j = 0; j < 4; ++j) acc[m][n][j] = 0.0f;

  const int alane = lane & 15;
  const int sw = lane & 7;
  const int s0 = lane >> 4;
  const int slot0 = ((s0 ^ sw) * 16);
  const int slot1 = (((s0 + 4) ^ sw) * 16);
  const int aBase = (wr * 64 + alane) * 128;  // + imm mh*16384 + ms*2048
  const int bBase = (wc * 32 + alane) * 128;  // + imm nh*16384 + ns*2048

  short8 aF[4][2];     // [ms][kk], current mh
  short8 bF[2][2][2];  // [nh][ns][kk], both halves live

#define ARD8(MH, AR0, AR1)                           \
  _Pragma("unroll") for (int ms = 0; ms < 4; ++ms) { \
    DSR(aF[ms][0], AR0, (MH)*16384 + ms * 2048);     \
    DSR(aF[ms][1], AR1, (MH)*16384 + ms * 2048);     \
  }
#define BRD4(NH, BR0, BR1)                           \
  _Pragma("unroll") for (int ns = 0; ns < 2; ++ns) { \
    DSR(bF[NH][ns][0], BR0, (NH)*16384 + ns * 2048); \
    DSR(bF[NH][ns][1], BR1, (NH)*16384 + ns * 2048); \
  }
#define MFMA_Q(MH, NH)                                                     \
  do {                                                                     \
    __builtin_amdgcn_s_setprio(1);                                         \
    _Pragma("unroll") for (int ms = 0; ms < 4; ++ms)                       \
    _Pragma("unroll") for (int ns = 0; ns < 2; ++ns)                       \
    _Pragma("unroll") for (int kk = 0; kk < 2; ++kk)                       \
        acc[(MH)*4 + ms][(NH)*2 + ns] =                                    \
            __builtin_amdgcn_mfma_f32_16x16x32_bf16(                       \
                aF[ms][kk], bF[NH][ns][kk], acc[(MH)*4 + ms][(NH)*2 + ns], \
                0, 0, 0);                                                  \
    __builtin_amdgcn_s_setprio(0);                                         \
    __builtin_amdgcn_sched_barrier(0);                                     \
  } while (0)

// One K-tile: 4 quadrant phases, all reads pre-barrier, lgkm(0) post-barrier.
#define TILE_BODY(BUF, KT)                                            \
  do {                                                                \
    const long ko = (long)(((KT) + 1 < NT) ? (KT) + 1 : (KT)) * 64;   \
    const int aR0 = (BUF)*32768 + aBase + slot0;                      \
    const int aR1 = (BUF)*32768 + aBase + slot1;                      \
    const int bR0 = 65536 + (BUF)*32768 + bBase + slot0;              \
    const int bR1 = 65536 + (BUF)*32768 + bBase + slot1;              \
    /* p0: Q(mh0,nh0) */                                              \
    ARD8(0, aR0, aR1);                                                \
    BRD4(0, bR0, bR1);                                                \
    SA(0, (BUF) ^ 1, ko);                                             \
    VMC4();                                                           \
    BARRIER();                                                        \
    LGKM0();                                                          \
    MFMA_Q(0, 0);                                                     \
    /* p1: Q(mh0,nh1) */                                              \
    BRD4(1, bR0, bR1);                                                \
    SB(0, (BUF) ^ 1, ko);                                             \
    VMC4();                                                           \
    BARRIER();                                                        \
    LGKM0();                                                          \
    MFMA_Q(0, 1);                                                     \
    /* p2: Q(mh1,nh1) */                                              \
    ARD8(1, aR0, aR1);                                                \
    SB(1, (BUF) ^ 1, ko);                                             \
    BARRIER();                                                        \
    LGKM0();                                                          \
    MFMA_Q(1, 1);                                                     \
    /* p3: Q(mh1,nh0) (all frags held) */                             \
    SA(1, (BUF) ^ 1, ko);                                             \
    VMC4();                                                           \
    BARRIER();                                                        \
    MFMA_Q(1, 0);                                                     \
  } while (0)

  for (int t2 = 0; t2 < NT; t2 += 2) {
    TILE_BODY(0, t2);
    TILE_BODY(1, t2 + 1);
  }
#undef TILE_BODY
#undef ARD8
#undef BRD4
#undef MFMA_Q
#undef SA
#undef SB

  // ---------------- epilogue ----------------
  const int rsub = (lane >> 4) * 4;

  if constexpr (MODE == 0) {
    // A=W-stack: acc row = out-d, col = token. which = bm>>10 per block.
    const int which = bm >> 10;
    const float* bp = which == 0 ? bias0 : (which == 1 ? bias1 : bias2);
    u16* Cq = (u16*)C0;
    u16* Ck = (u16*)C1;
    u16* Cvt = (u16*)C2;  // VT base [b][d][kv]
    const int od_base = (bm & 1023) + wr * 128 + rsub;
    if (which == 2) {
      // V: acc is already V^T -- write VT[b][d][SCC+s] directly.
#pragma unroll
      for (int n = 0; n < 4; ++n) {
        int token = bn + wc * 64 + n * 16 + alane;
        int b = token >> 11, ss = token & 2047;
        u16* vtb = Cvt + (long)b * DM * SKV + SCC + ss;
#pragma unroll
        for (int m = 0; m < 8; ++m) {
          int cc = od_base + m * 16;
          float4 bb = *(const float4*)(bp + cc);
          float bv4[4] = {bb.x, bb.y, bb.z, bb.w};
#pragma unroll
          for (int jj = 0; jj < 4; ++jj)
            vtb[(long)(cc + jj) * SKV] = f2bf(acc[m][n][jj] + bv4[jj]);
        }
      }
    } else {
#pragma unroll
      for (int n = 0; n < 4; ++n) {
        int token = bn + wc * 64 + n * 16 + alane;
        u16* dst;
        if (which == 1) {
          int b = token >> 11, ss = token & 2047;
          dst = Ck + ((long)b * SKV + SCC + ss) * DM;
        } else {
          dst = Cq + (long)token * DM;
        }
#pragma unroll
        for (int m = 0; m < 8; ++m) {
          int cc = od_base + m * 16;
          float4 bb = *(const float4*)(bp + cc);
          ushort4 u;
          u.x = f2bf(acc[m][n][0] + bb.x);
          u.y = f2bf(acc[m][n][1] + bb.y);
          u.z = f2bf(acc[m][n][2] + bb.z);
          u.w = f2bf(acc[m][n][3] + bb.w);
          *(ushort4*)(dst + cc) = u;
        }
      }
    }
  } else if constexpr (MODE == 1) {
    // A=K: acc row = kv, col = q. store P[q][kv] ushort4; rowsum per q.
    u16* Pp = (u16*)C0 + (long)z * SQN * SKV;
    float* sb = sums + z * SQN;
    const float CE = 0.18033688011112042f;  // log2(e)/8
    const int kv_base = bm + wr * 128 + rsub;
#pragma unroll
    for (int n = 0; n < 4; ++n) {
      int q = bn + wc * 64 + n * 16 + alane;
      u16* prow = Pp + (long)q * SKV;
      float part = 0.f;
#pragma unroll
      for (int m = 0; m < 8; ++m) {
        int kv = kv_base + m * 16;
        float e0 = exp2f(acc[m][n][0] * CE);
        float e1 = exp2f(acc[m][n][1] * CE);
        float e2 = exp2f(acc[m][n][2] * CE);
        float e3 = exp2f(acc[m][n][3] * CE);
        part += (e0 + e1) + (e2 + e3);
        ushort4 u;
        u.x = f2bf(e0); u.y = f2bf(e1); u.z = f2bf(e2); u.w = f2bf(e3);
        *(ushort4*)(prow + kv) = u;
      }
      part += __shfl_xor(part, 16);
      part += __shfl_xor(part, 32);
      if ((lane >> 4) == 0) atomicAdd(&sb[q], part);
    }
  } else {
    // acc row = q, col = d. f32 stores, 64B sectors.
    float* Cp = (float*)C0 + (long)z * SQN * DM;
#pragma unroll
    for (int n = 0; n < 4; ++n) {
      int col = bn + wc * 64 + n * 16 + alane;
#pragma unroll
      for (int m = 0; m < 8; ++m)
#pragma unroll
        for (int j = 0; j < 4; ++j) {
          int row = bm + wr * 128 + m * 16 + rsub + j;
          Cp[(long)row * DM + col] = acc[m][n][j];
        }
    }
  }
}

// ---------------- reduce split-K partials + normalize ----------------
__global__ __launch_bounds__(256) void k_reduce(const float* __restrict__ Op,
                                                const float* __restrict__ sums,
                                                float* __restrict__ out) {
  const long n4 = (long)NB * SQN * DM / 4;
  long i = (long)blockIdx.x * 256 + threadIdx.x;
  if (i >= n4) return;
  long e = i * 4;
  int b = (int)(e / ((long)SQN * DM));
  long rem = e - (long)b * SQN * DM;
  int row = (int)(rem / DM);
  const long z4 = (long)SQN * DM / 4;
  long i0 = (long)(b * NSPLIT) * z4 + (rem >> 2);
  float4 a0 = ((const float4*)Op)[i0];
  float4 a1 = ((const float4*)Op)[i0 + z4];
  float inv = 1.0f / sums[b * SQN + row];
  float4 r;
  r.x = (a0.x + a1.x) * inv;
  r.y = (a0.y + a1.y) * inv;
  r.z = (a0.z + a1.z) * inv;
  r.w = (a0.w + a1.w) * inv;
  ((float4*)out)[i] = r;
}

// ---------------- launch ----------------
extern "C" void kernel_launch(void* const* d_in, const int* in_sizes, int n_in,
                              void* d_out, int out_size, void* d_ws, size_t ws_size,
                              hipStream_t stream) {
  const float* hidden = (const float*)d_in[0];
  const float* ck = (const float*)d_in[1];
  const float* cv = (const float*)d_in[2];
  const float* Wq = (const float*)d_in[3];
  const float* bq = (const float*)d_in[4];
  const float* Wk = (const float*)d_in[5];
  const float* bk = (const float*)d_in[6];
  const float* Wv = (const float*)d_in[7];
  const float* bv = (const float*)d_in[8];
  (void)in_sizes; (void)n_in; (void)out_size; (void)ws_size;

  hipFuncSetAttribute(reinterpret_cast<const void*>(&k_gemm8<0>),
                      hipFuncAttributeMaxDynamicSharedMemorySize, 131072);
  hipFuncSetAttribute(reinterpret_cast<const void*>(&k_gemm8<1>),
                      hipFuncAttributeMaxDynamicSharedMemorySize, 131072);
  hipFuncSetAttribute(reinterpret_cast<const void*>(&k_gemm8<2>),
                      hipFuncAttributeMaxDynamicSharedMemorySize, 131072);

  char* base = (char*)d_ws;
  size_t off = 0;
  auto alloc = [&](size_t bytes) {
    char* p = base + off;
    off = (off + bytes + 255) & ~(size_t)255;
    return p;
  };
  // region0 (dead before PV): Hb, weights, Qb, Kb. Opart aliases it.
  u16* Hb = (u16*)alloc((size_t)NB * SQN * DM * 2);
  u16* Wall = (u16*)alloc((size_t)3 * DM * DM * 2);  // Wq|Wk|Wv stacked
  u16* Qb = (u16*)alloc((size_t)NB * SQN * DM * 2);
  u16* Kb = (u16*)alloc((size_t)NB * SKV * DM * 2);
  float* Opart = (float*)base;  // [NB*NSPLIT][2048][1024] f32, aliases region0
  size_t opart_bytes = (size_t)NB * NSPLIT * SQN * DM * 4;
  if (off < opart_bytes) off = (opart_bytes + 255) & ~(size_t)255;
  u16* VT = (u16*)alloc((size_t)NB * DM * SKV * 2);
  u16* P = (u16*)alloc((size_t)NB * SQN * SKV * 2);
  float* sums = (float*)alloc((size_t)NB * SQN * 4);

  // fused prep: all conversions + sums zeroing in one dispatch
  k_prep<<<2048, 256, 0, stream>>>(hidden, Wq, Wk, Wv, ck, Hb, Wall, Kb, sums);

  // fused QKV projection: A=W-stack [3072][1024], B=H [8192][1024];
  // V third writes VT[.., SCC..SKV) directly.
  k_gemm8<0><<<dim3(32, 12, 1), 512, 131072, stream>>>(
      Wall, Hb, Qb, Kb, VT, nullptr, bq, bk, bv);

  // V^T cached region (kv < SCC)
  k_build_vt<<<dim3(SCC / 64, DM / 64, NB), 256, 0, stream>>>(cv, VT);

  // S^T = K.Q^T, transposed grid: x walks K-panels, y holds Q-panel
  k_gemm8<1><<<dim3(SKV / 256, SQN / 256, NB), 512, 131072, stream>>>(
      Kb, Qb, P, nullptr, nullptr, sums, nullptr, nullptr, nullptr);

  // PV split-K(2): A=P, B=VT
  k_gemm8<2><<<dim3(DM / 256, SQN / 256, NB * NSPLIT), 512, 131072, stream>>>(
      P, VT, Opart, nullptr, nullptr, nullptr, nullptr, nullptr, nullptr);

  // reduce partials + normalize
  k_reduce<<<(NB * SQN * DM / 4 + 255) / 256, 256, 0, stream>>>(
      Opart, sums, (float*)d_out);
}